// Round 1
// 10464.375 us; speedup vs baseline: 1.5127x; 1.5127x over previous
//
#include <hip/hip_runtime.h>
#include <hip/hip_bf16.h>
#include <math.h>

// R16: perf round, numerics BIT-IDENTICAL to R15 (the passing 15.8ms run).
// Diagnosis: fp64 encoder convs are cache-latency bound (VALUBusy 24%,
// HBM 1.7%): COT=4, no LDS tiling => each input element re-fetched ~36x
// from L2/L3 (134MB fp64 input >> 4MB/XCD L2). Fix:
//  - conv_tiled: LDS-staged tiled conv (16x16 output tile, 32 couts/block,
//    halo zero-padded in LDS, IN_RELU at stage time). Accumulation order per
//    output (ci,kh,kw ascending) identical to the direct kernel; fma(0,w,acc)
//    on halo zeros is bit-exact (acc never -0 here). Used for enc2(4x4s2),
//    enc3, enc res 3x3s, dec1, dec res 3x3s.
//  - COT 4->8 for the 1x1 convs and dt1 deconv (order-preserving, halves
//    redundant input reads).
// Pipeline semantics unchanged: fp64 encoder -> fp32 z, np-exact fp32 VQ,
// straight-through fl(z+fl(q-z)), fp32 decoder, fp32 output writes.

template<typename T> __device__ __forceinline__ T fmaT(T a, T b, T c);
template<> __device__ __forceinline__ double fmaT(double a, double b, double c) { return fma(a, b, c); }
template<> __device__ __forceinline__ float  fmaT(float a, float b, float c)    { return fmaf(a, b, c); }
template<typename T> __device__ __forceinline__ T maxT(T a, T b);
template<> __device__ __forceinline__ double maxT(double a, double b) { return fmax(a, b); }
template<> __device__ __forceinline__ float  maxT(float a, float b)   { return fmaxf(a, b); }

// ---------------------------------------------------------------------------
// LDS-tiled conv, pad=1. 256 threads = 4 waves. Block computes a 16x16 output
// tile x 32 output channels. Wave w -> couts [co0+w*8, +8); lane: owg=l&3
// (4 pixels), oh=l>>2 (16 rows). Input tile (15*S+K)^2 staged in LDS per NCI
// input channels, zero-padded OOB, IN_RELU applied at stage time.
// Accumulation per output: ci asc, kh asc, kw asc — identical to direct kernel.
// ---------------------------------------------------------------------------
template<typename T, int K, int S, bool IN_RELU, bool OUT_RELU, int NCI>
__global__ __launch_bounds__(256, 3)
void conv_tiled(const T* __restrict__ in, const float* __restrict__ w,
                const float* __restrict__ bias, T* __restrict__ out,
                int B, int Cin, int Hin, int Win, int Cout, int Hout, int Wout)
{
    constexpr int TILE = 16;
    constexpr int IT   = (TILE - 1) * S + K;   // input tile edge incl. halo
    constexpr int ITT  = IT * IT;
    constexpr int COB  = 32;                   // couts per block
    constexpr int CPW  = COB / 4;              // couts per wave (= per thread)
    constexpr int PIX  = 4;
    constexpr int WIN  = (PIX - 1) * S + K;

    __shared__ T tile[NCI * ITT];

    int ntx = Wout / TILE, nty = Hout / TILE, ncb = Cout / COB;
    int g = blockIdx.x;
    int tx = g % ntx; g /= ntx;
    int ty = g % nty; g /= nty;
    int cb = g % ncb;
    int b  = g / ncb;

    int t    = threadIdx.x;
    int wave = t >> 6;
    int lowg = t & 3;
    int loh  = (t >> 2) & 15;
    int co0  = cb * COB + wave * CPW;
    int oh0t = ty * TILE, ow0t = tx * TILE;
    int oh   = oh0t + loh;
    int ow0  = ow0t + lowg * PIX;

    T acc[CPW][PIX];
    #pragma unroll
    for (int c = 0; c < CPW; c++) {
        T bv = (T)bias[co0 + c];
        #pragma unroll
        for (int j = 0; j < PIX; j++) acc[c][j] = bv;
    }

    const int ihb = oh0t * S - 1;              // pad = 1
    const int iwb = ow0t * S - 1;
    const long inHW = (long)Hin * Win;
    const int KK  = K * K;
    const int wCK = Cin * KK;

    for (int ci0 = 0; ci0 < Cin; ci0 += NCI) {
        __syncthreads();
        for (int e = t; e < NCI * ITT; e += 256) {
            int c  = e / ITT, r = e - c * ITT;
            int rr = r / IT,  cc = r - rr * IT;
            int ih = ihb + rr, iw = iwb + cc;
            T v = (T)0;
            if ((unsigned)ih < (unsigned)Hin && (unsigned)iw < (unsigned)Win)
                v = in[((long)b * Cin + ci0 + c) * inHW + (long)ih * Win + iw];
            if (IN_RELU) v = maxT(v, (T)0);
            tile[e] = v;
        }
        __syncthreads();
        #pragma unroll
        for (int c = 0; c < NCI; c++) {
            const float* wp = w + ((long)co0 * Cin + (ci0 + c)) * KK;
            #pragma unroll
            for (int kh = 0; kh < K; kh++) {
                const T* rp = tile + c * ITT + (loh * S + kh) * IT + lowg * PIX * S;
                T iv[WIN];
                #pragma unroll
                for (int x = 0; x < WIN; x++) iv[x] = rp[x];
                #pragma unroll
                for (int c2 = 0; c2 < CPW; c2++) {
                    #pragma unroll
                    for (int kw = 0; kw < K; kw++) {
                        T wv = (T)wp[c2 * wCK + kh * K + kw];
                        #pragma unroll
                        for (int j = 0; j < PIX; j++)
                            acc[c2][j] = fmaT(iv[j * S + kw], wv, acc[c2][j]);
                    }
                }
            }
        }
    }

    long ostride = (long)Hout * Wout;
    long obase = (((long)b * Cout + co0) * Hout + oh) * Wout + ow0;
    #pragma unroll
    for (int c = 0; c < CPW; c++) {
        #pragma unroll
        for (int j = 0; j < PIX; j++) {
            T v = acc[c][j];
            if (OUT_RELU) v = maxT(v, (T)0);
            out[obase + c * ostride + j] = v;
        }
    }
}

// ---------------------------------------------------------------------------
// Encoder direct conv, fp64 accumulate (used: enc1, 1x1 convs). COT templated.
// ---------------------------------------------------------------------------
template<int K, int STRIDE, int PAD, bool IN_RELU, bool OUT_RELU, bool RES_ADD,
         int COT, typename TIn, typename TOut>
__global__ __launch_bounds__(256)
void conv_enc64(const TIn* __restrict__ in, const float* __restrict__ w,
                const float* __restrict__ bias, const double* __restrict__ res,
                TOut* __restrict__ out,
                int B, int Cin, int Hin, int Win, int Cout, int Hout, int Wout)
{
    constexpr int PIX = 4;
    constexpr int WIN = STRIDE * (PIX - 1) + K;
    int wg = Wout >> 2;
    int ncog = Cout / COT;
    long idx = (long)blockIdx.x * 256 + threadIdx.x;
    long total = (long)B * ncog * Hout * wg;
    if (idx >= total) return;
    int owg = (int)(idx % wg);  long t = idx / wg;
    int oh  = (int)(t % Hout);  t /= Hout;
    int cog = (int)(t % ncog);
    int b   = (int)(t / ncog);
    int ow0 = owg << 2, co0 = cog * COT;

    double acc[COT][PIX];
    #pragma unroll
    for (int c = 0; c < COT; c++) {
        double bv = (double)bias[co0 + c];
        #pragma unroll
        for (int j = 0; j < PIX; j++) acc[c][j] = bv;
    }

    const int ih0 = oh * STRIDE - PAD;
    const int iwb = ow0 * STRIDE - PAD;
    const long inCH = (long)Hin * Win;
    const int  wCK  = Cin * K * K;

    for (int ci = 0; ci < Cin; ci++) {
        const TIn* inp = in + ((long)b * Cin + ci) * inCH;
        const float* wp = w + ((long)co0 * Cin + ci) * (K * K);
        #pragma unroll
        for (int kh = 0; kh < K; kh++) {
            int ih = ih0 + kh;
            if ((unsigned)ih >= (unsigned)Hin) continue;
            const TIn* rowp = inp + (long)ih * Win;
            double iv[WIN];
            #pragma unroll
            for (int x = 0; x < WIN; x++) {
                int iw = iwb + x;
                double v = ((unsigned)iw < (unsigned)Win) ? (double)rowp[iw] : 0.0;
                iv[x] = IN_RELU ? fmax(v, 0.0) : v;
            }
            #pragma unroll
            for (int c = 0; c < COT; c++) {
                #pragma unroll
                for (int kw = 0; kw < K; kw++) {
                    double wv = (double)wp[c * wCK + kh * K + kw];
                    #pragma unroll
                    for (int j = 0; j < PIX; j++)
                        acc[c][j] = fma(iv[j * STRIDE + kw], wv, acc[c][j]);
                }
            }
        }
    }

    long ostride = (long)Hout * Wout;
    long obase = (((long)b * Cout + co0) * Hout + oh) * Wout + ow0;
    #pragma unroll
    for (int c = 0; c < COT; c++) {
        #pragma unroll
        for (int j = 0; j < PIX; j++) {
            double v = acc[c][j];
            if (RES_ADD) v += res[obase + c * ostride + j];
            if (OUT_RELU) v = fmax(v, 0.0);
            out[obase + c * ostride + j] = (TOut)v;
        }
    }
}

// ---------------------------------------------------------------------------
// Decoder direct conv, fp32 (used: 1x1 convs). COT templated.
// ---------------------------------------------------------------------------
template<int K, int STRIDE, int PAD, bool IN_RELU, bool OUT_RELU, bool RES_ADD, int COT>
__global__ __launch_bounds__(256)
void conv_direct(const float* __restrict__ in, const float* __restrict__ w,
                 const float* __restrict__ bias, const float* __restrict__ res,
                 float* __restrict__ out,
                 int B, int Cin, int Hin, int Win, int Cout, int Hout, int Wout)
{
    constexpr int PIX = 4;
    constexpr int WIN = STRIDE * (PIX - 1) + K;
    int wg = Wout >> 2;
    int ncog = Cout / COT;
    long idx = (long)blockIdx.x * 256 + threadIdx.x;
    long total = (long)B * ncog * Hout * wg;
    if (idx >= total) return;
    int owg = (int)(idx % wg);  long t = idx / wg;
    int oh  = (int)(t % Hout);  t /= Hout;
    int cog = (int)(t % ncog);
    int b   = (int)(t / ncog);
    int ow0 = owg << 2, co0 = cog * COT;

    float acc[COT][PIX];
    #pragma unroll
    for (int c = 0; c < COT; c++) {
        float bv = bias[co0 + c];
        #pragma unroll
        for (int j = 0; j < PIX; j++) acc[c][j] = bv;
    }

    const int ih0 = oh * STRIDE - PAD;
    const int iwb = ow0 * STRIDE - PAD;
    const long inCH = (long)Hin * Win;
    const int  wCK  = Cin * K * K;

    for (int ci = 0; ci < Cin; ci++) {
        const float* inp = in + ((long)b * Cin + ci) * inCH;
        const float* wp  = w + ((long)co0 * Cin + ci) * (K * K);
        #pragma unroll
        for (int kh = 0; kh < K; kh++) {
            int ih = ih0 + kh;
            if ((unsigned)ih >= (unsigned)Hin) continue;
            const float* rowp = inp + (long)ih * Win;
            float iv[WIN];
            #pragma unroll
            for (int x = 0; x < WIN; x++) {
                int iw = iwb + x;
                float v = ((unsigned)iw < (unsigned)Win) ? rowp[iw] : 0.f;
                iv[x] = IN_RELU ? fmaxf(v, 0.f) : v;
            }
            #pragma unroll
            for (int c = 0; c < COT; c++) {
                #pragma unroll
                for (int kw = 0; kw < K; kw++) {
                    float wv = wp[c * wCK + kh * K + kw];
                    #pragma unroll
                    for (int j = 0; j < PIX; j++)
                        acc[c][j] = fmaf(iv[j * STRIDE + kw], wv, acc[c][j]);
                }
            }
        }
    }

    long ostride = (long)Hout * Wout;
    long obase = (((long)b * Cout + co0) * Hout + oh) * Wout + ow0;
    #pragma unroll
    for (int c = 0; c < COT; c++) {
        #pragma unroll
        for (int j = 0; j < PIX; j++) {
            float v = acc[c][j];
            if (RES_ADD) v += res[obase + c * ostride + j];
            if (OUT_RELU) v = fmaxf(v, 0.f);
            out[obase + c * ostride + j] = v;
        }
    }
}

// ---------------------------------------------------------------------------
// ConvTranspose2d k=4 s=2 p=1, fp32. Weight (Cin, Cout, 4, 4). FP32 stores.
// ---------------------------------------------------------------------------
template<int COT, bool IN_RELU, bool OUT_RELU, bool OUT_TANH>
__global__ __launch_bounds__(256)
void deconv4x4s2(const float* __restrict__ in, const float* __restrict__ w,
                 const float* __restrict__ bias, float* __restrict__ out,
                 int B, int Cin, int Hin, int Win, int Cout)
{
    int Hout = Hin << 1, Wout = Win << 1;
    int wg = Wout >> 2;
    int ncog = Cout / COT;
    long idx = (long)blockIdx.x * 256 + threadIdx.x;
    long total = (long)B * ncog * Hout * wg;
    if (idx >= total) return;
    int owg = (int)(idx % wg);  long t = idx / wg;
    int oh  = (int)(t % Hout);  t /= Hout;
    int cog = (int)(t % ncog);
    int b   = (int)(t / ncog);
    int ow0 = owg << 2, co0 = cog * COT;

    float acc[COT][4];
    #pragma unroll
    for (int c = 0; c < COT; c++) {
        float bv = bias[co0 + c];
        #pragma unroll
        for (int j = 0; j < 4; j++) acc[c][j] = bv;
    }

    int ah  = (oh + 1) & 1;
    int iwb = ow0 >> 1;
    for (int ci = 0; ci < Cin; ci++) {
        const float* inp = in + ((long)b * Cin + ci) * ((long)Hin * Win);
        const float* wp  = w + ((long)ci * Cout + co0) * 16;
        #pragma unroll
        for (int th = 0; th < 2; th++) {
            int kh = ah + (th << 1);
            int ih = (oh + 1 - kh) >> 1;
            if ((unsigned)ih >= (unsigned)Hin) continue;
            const float* row = inp + (long)ih * Win;
            float i0 = (iwb - 1 >= 0) ? row[iwb - 1] : 0.f;
            float i1 = row[iwb];
            float i2 = row[iwb + 1];
            float i3 = (iwb + 2 < Win) ? row[iwb + 2] : 0.f;
            if (IN_RELU) {
                i0 = fmaxf(i0, 0.f); i1 = fmaxf(i1, 0.f);
                i2 = fmaxf(i2, 0.f); i3 = fmaxf(i3, 0.f);
            }
            #pragma unroll
            for (int c = 0; c < COT; c++) {
                const float* wk = wp + c * 16 + kh * 4;
                float w0 = wk[0], w1 = wk[1], w2 = wk[2], w3 = wk[3];
                acc[c][0] = fmaf(i1, w1, fmaf(i0, w3, acc[c][0]));
                acc[c][1] = fmaf(i2, w0, fmaf(i1, w2, acc[c][1]));
                acc[c][2] = fmaf(i2, w1, fmaf(i1, w3, acc[c][2]));
                acc[c][3] = fmaf(i3, w0, fmaf(i2, w2, acc[c][3]));
            }
        }
    }

    long ostride = (long)Hout * Wout;
    long obase = (((long)b * Cout + co0) * (long)Hout + oh) * Wout + ow0;
    #pragma unroll
    for (int c = 0; c < COT; c++) {
        #pragma unroll
        for (int j = 0; j < 4; j++) {
            float v = acc[c][j];
            if (OUT_RELU) v = fmaxf(v, 0.f);
            if (OUT_TANH) v = tanhf(v);
            out[obase + c * ostride + j] = v;   // fp32 store
        }
    }
}

// numpy pairwise sum-of-squares over 64 fp32 values.
__device__ __forceinline__ float np_sumsq64(const float* v) {
    float r[8];
    #pragma unroll
    for (int j = 0; j < 8; j++) r[j] = __fmul_rn(v[j], v[j]);
    #pragma unroll
    for (int i = 8; i < 64; i += 8) {
        #pragma unroll
        for (int j = 0; j < 8; j++)
            r[j] = __fadd_rn(r[j], __fmul_rn(v[i + j], v[i + j]));
    }
    float s01 = __fadd_rn(r[0], r[1]), s23 = __fadd_rn(r[2], r[3]);
    float s45 = __fadd_rn(r[4], r[5]), s67 = __fadd_rn(r[6], r[7]);
    return __fadd_rn(__fadd_rn(s01, s23), __fadd_rn(s45, s67));
}

__global__ void codenorm_kernel(const float* __restrict__ cb, float* __restrict__ cn)
{
    int k = blockIdx.x * 64 + threadIdx.x;
    if (k >= 512) return;
    float row[64];
    #pragma unroll
    for (int d = 0; d < 64; d++) row[d] = cb[k * 64 + d];
    cn[k] = np_sumsq64(row);
}

// VQ: np-exact fp32 chain; st = fl(z + fl(q-z)).
__global__ __launch_bounds__(256)
void vq_kernel(const float* __restrict__ z, const float* __restrict__ cb,
               const float* __restrict__ cn, float* __restrict__ st,
               double* __restrict__ loss_sum, int B)
{
    long idx = (long)blockIdx.x * 256 + threadIdx.x;
    if (idx >= (long)B * 4096) return;
    int p = (int)(idx & 4095);
    int b = (int)(idx >> 12);
    const float* zp = z + (long)b * 64 * 4096 + p;
    float zr[64];
    #pragma unroll
    for (int d = 0; d < 64; d++) zr[d] = zp[(long)d * 4096];

    float s1 = np_sumsq64(zr);

    float best = INFINITY;
    int bi = 0;
    for (int k = 0; k < 512; k++) {
        const float* ck = cb + k * 64;
        float m = 0.f;
        #pragma unroll
        for (int d = 0; d < 64; d++) m = fmaf(zr[d], ck[d], m);
        float dist = __fadd_rn(__fsub_rn(s1, __fmul_rn(2.f, m)), cn[k]);
        if (dist < best) { best = dist; bi = k; }
    }

    const float* cbest = cb + bi * 64;
    float* sp = st + (long)b * 64 * 4096 + p;
    double ls = 0.0;
    #pragma unroll
    for (int d = 0; d < 64; d++) {
        float qv = cbest[d];
        float diff = __fsub_rn(qv, zr[d]);
        double dd = (double)qv - (double)zr[d];
        ls += dd * dd;
        sp[(long)d * 4096] = __fadd_rn(zr[d], diff);
    }
    #pragma unroll
    for (int off = 32; off > 0; off >>= 1) ls += __shfl_down(ls, off, 64);
    if ((threadIdx.x & 63) == 0) atomicAdd(loss_sum, ls);
}

__global__ void loss_final_kernel(const double* __restrict__ s, float* __restrict__ out)
{
    out[0] = (float)(1.25 * s[0] / 8388608.0);   // fp32 loss store
}

static inline int nblk(long total) { return (int)((total + 255) / 256); }

extern "C" void kernel_launch(void* const* d_in, const int* in_sizes, int n_in,
                              void* d_out, int out_size, void* d_ws, size_t ws_size,
                              hipStream_t stream)
{
    const float* x        = (const float*)d_in[0];
    const float* enc_w1   = (const float*)d_in[1];
    const float* enc_b1   = (const float*)d_in[2];
    const float* enc_w2   = (const float*)d_in[3];
    const float* enc_b2   = (const float*)d_in[4];
    const float* enc_w3   = (const float*)d_in[5];
    const float* enc_b3   = (const float*)d_in[6];
    const float* enc_rw1  = (const float*)d_in[7];
    const float* enc_rb1  = (const float*)d_in[8];
    const float* enc_rw2  = (const float*)d_in[9];
    const float* enc_rb2  = (const float*)d_in[10];
    const float* pvq_w    = (const float*)d_in[11];
    const float* pvq_b    = (const float*)d_in[12];
    const float* codebook = (const float*)d_in[13];
    const float* dec_w1   = (const float*)d_in[14];
    const float* dec_b1   = (const float*)d_in[15];
    const float* dec_rw1  = (const float*)d_in[16];
    const float* dec_rb1  = (const float*)d_in[17];
    const float* dec_rw2  = (const float*)d_in[18];
    const float* dec_rb2  = (const float*)d_in[19];
    const float* dt1_w    = (const float*)d_in[20];
    const float* dt1_b    = (const float*)d_in[21];
    const float* dt2_w    = (const float*)d_in[22];
    const float* dt2_b    = (const float*)d_in[23];

    float* out = (float*)d_out;            // fp32 output buffer (ref dtype)
    char* wsb = (char*)d_ws;

    float*  CN = (float*)wsb;              // 512 floats
    double* LS = (double*)(wsb + 4096);    // 1 double
    const size_t SMALLB = 4352;

    const long eA = 1048576, eB = 524288, eC = 524288, eT = 131072;
    const long eZ = 262144, eQ = 262144;
    const size_t perSampleB = (size_t)(eA + eB + eC + eT) * 8 + (size_t)(eZ + eQ) * 4;

    int Bc = 32;
    while (Bc > 1 && SMALLB + perSampleB * Bc + 1024 > ws_size) Bc >>= 1;
    const int nChunks = 32 / Bc;

    double* A64 = (double*)(wsb + SMALLB);
    double* B64 = A64 + eA * Bc;
    double* C64 = B64 + eB * Bc;
    double* T64 = C64 + eC * Bc;
    float*  Z32 = (float*)(T64 + eT * Bc);
    float*  Qf  = Z32 + eZ * Bc;
    float* Df = (float*)B64;   // decoder fp32 aliases (encoder buffers dead)
    float* Tf = (float*)T64;
    float* Ef = (float*)A64;

    hipMemsetAsync(LS, 0, sizeof(double), stream);
    codenorm_kernel<<<8, 64, 0, stream>>>(codebook, CN);

    for (int c = 0; c < nChunks; c++) {
        const float* xc = x + (long)c * Bc * 3 * 65536;
        float* outc = out + (long)c * Bc * 3 * 65536;

        // ---- encoder (fp64 accumulate -> fp32 z) ----
        conv_enc64<4,2,1,false,true,false,4><<<nblk((long)Bc*16*128*32), 256, 0, stream>>>(
            xc, enc_w1, enc_b1, nullptr, A64, Bc, 3, 256, 256, 64, 128, 128);
        // enc2: 4x4 s2 64->128, out 64x64, OUT_RELU — tiled (NCI=2, 18.5KB LDS)
        conv_tiled<double,4,2,false,true,2><<<Bc*4*4*4, 256, 0, stream>>>(
            A64, enc_w2, enc_b2, B64, Bc, 64, 128, 128, 128, 64, 64);
        // enc3: 3x3 s1 128->128 — tiled
        conv_tiled<double,3,1,false,false,4><<<Bc*4*4*4, 256, 0, stream>>>(
            B64, enc_w3, enc_b3, C64, Bc, 128, 64, 64, 128, 64, 64);
        for (int i = 0; i < 2; i++) {
            conv_tiled<double,3,1,true,false,4><<<Bc*4*4*1, 256, 0, stream>>>(
                C64, enc_rw1 + (long)i*32*128*9, enc_rb1 + i*32, T64,
                Bc, 128, 64, 64, 32, 64, 64);
            conv_enc64<1,1,0,true,false,true,8><<<nblk((long)Bc*16*64*16), 256, 0, stream>>>(
                T64, enc_rw2 + (long)i*128*32, enc_rb2 + i*128, C64, C64,
                Bc, 32, 64, 64, 128, 64, 64);
        }
        conv_enc64<1,1,0,true,false,false,8><<<nblk((long)Bc*8*64*16), 256, 0, stream>>>(
            C64, pvq_w, pvq_b, nullptr, Z32, Bc, 128, 64, 64, 64, 64, 64);

        // ---- VQ (np-exact fp32) ----
        vq_kernel<<<Bc * 16, 256, 0, stream>>>(Z32, codebook, CN, Qf, LS, Bc);

        // ---- decoder (fp32), fp32 output stores ----
        conv_tiled<float,3,1,false,false,8><<<Bc*4*4*4, 256, 0, stream>>>(
            Qf, dec_w1, dec_b1, Df, Bc, 64, 64, 64, 128, 64, 64);
        for (int i = 0; i < 2; i++) {
            conv_tiled<float,3,1,true,false,8><<<Bc*4*4*1, 256, 0, stream>>>(
                Df, dec_rw1 + (long)i*32*128*9, dec_rb1 + i*32, Tf,
                Bc, 128, 64, 64, 32, 64, 64);
            conv_direct<1,1,0,true,false,true,8><<<nblk((long)Bc*16*64*16), 256, 0, stream>>>(
                Tf, dec_rw2 + (long)i*128*32, dec_rb2 + i*128, Df, Df,
                Bc, 32, 64, 64, 128, 64, 64);
        }
        deconv4x4s2<8,true,true,false><<<nblk((long)Bc*8*128*32), 256, 0, stream>>>(
            Df, dt1_w, dt1_b, Ef, Bc, 128, 64, 64, 64);
        deconv4x4s2<3,false,false,true><<<nblk((long)Bc*1*256*64), 256, 0, stream>>>(
            Ef, dt2_w, dt2_b, outc, Bc, 64, 128, 128, 3);
    }

    loss_final_kernel<<<1, 1, 0, stream>>>(LS, out + 6291456);
}

// Round 2
// 8427.941 us; speedup vs baseline: 1.8782x; 1.2416x over previous
//
#include <hip/hip_runtime.h>
#include <hip/hip_bf16.h>
#include <math.h>

// R17: latency-slop elimination, numerics BIT-IDENTICAL to R16/R15.
//  - deconv_tiled: LDS-staged ConvTranspose2d(4,2,1) for dt1/dt2. Each thread
//    owns one input position, computes its 2x2 output quad with the EXACT
//    per-output fmaf chain of deconv4x4s2 (tap order kh=ah,ah+2; w3->w1 /
//    w2->w0). Halo zero-pad == original's skip (fma(0,w,acc) bit-exact).
//  - conv_tiled generalized (TIn/TAcc/TOut, PAD, RES_ADD, COB): now also
//    covers enc1 (fp32 in, fp64 acc), the 1x1 res2 convs (+residual) and pvq.
//  - vq_kernel: coalesced z loads via LDS transpose (values bit-identical),
//    4-way independent-k unroll (per-k fmaf chain unchanged, strict-< in
//    ascending k order preserved).
//  - COB=16 for Cout=32 res1 convs (grid 512->1024 blocks).
// Pipeline: fp64 encoder -> fp32 z, np-exact fp32 VQ, straight-through
// fl(z+fl(q-z)), fp32 decoder, fp32 output writes.

template<typename T> __device__ __forceinline__ T fmaT(T a, T b, T c);
template<> __device__ __forceinline__ double fmaT(double a, double b, double c) { return fma(a, b, c); }
template<> __device__ __forceinline__ float  fmaT(float a, float b, float c)    { return fmaf(a, b, c); }
template<typename T> __device__ __forceinline__ T maxT(T a, T b);
template<> __device__ __forceinline__ double maxT(double a, double b) { return fmax(a, b); }
template<> __device__ __forceinline__ float  maxT(float a, float b)   { return fmaxf(a, b); }

// ---------------------------------------------------------------------------
// LDS-tiled conv. 256 threads = 4 waves. Block computes a 16x16 output tile x
// COB output channels. Wave w -> couts [co0+w*CPW, +CPW); lane: owg=l&3,
// oh=l>>2. Input tile (15*S+K)^2 staged in LDS per NCI input channels,
// zero-padded OOB, IN_RELU at stage time (input converted TIn->TAcc first,
// matching the direct kernels). Accumulation per output: ci asc, kh asc,
// kw asc — bit-identical to the direct kernels.
// ---------------------------------------------------------------------------
template<typename TIn, typename TAcc, typename TOut, int K, int S, int PAD,
         bool IN_RELU, bool OUT_RELU, bool RES_ADD, int NCI, int COB>
__global__ __launch_bounds__(256, 3)
void conv_tiled(const TIn* __restrict__ in, const float* __restrict__ w,
                const float* __restrict__ bias, const TAcc* __restrict__ res,
                TOut* __restrict__ out,
                int B, int Cin, int Hin, int Win, int Cout, int Hout, int Wout)
{
    constexpr int TILE = 16;
    constexpr int IT   = (TILE - 1) * S + K;   // input tile edge incl. halo
    constexpr int ITT  = IT * IT;
    constexpr int CPW  = COB / 4;              // couts per wave (= per thread)
    constexpr int PIX  = 4;
    constexpr int WIN  = (PIX - 1) * S + K;

    __shared__ TAcc tile[NCI * ITT];

    int ntx = Wout / TILE, nty = Hout / TILE, ncb = Cout / COB;
    int g = blockIdx.x;
    int tx = g % ntx; g /= ntx;
    int ty = g % nty; g /= nty;
    int cb = g % ncb;
    int b  = g / ncb;

    int t    = threadIdx.x;
    int wave = t >> 6;
    int lowg = t & 3;
    int loh  = (t >> 2) & 15;
    int co0  = cb * COB + wave * CPW;
    int oh0t = ty * TILE, ow0t = tx * TILE;
    int oh   = oh0t + loh;
    int ow0  = ow0t + lowg * PIX;

    TAcc acc[CPW][PIX];
    #pragma unroll
    for (int c = 0; c < CPW; c++) {
        TAcc bv = (TAcc)bias[co0 + c];
        #pragma unroll
        for (int j = 0; j < PIX; j++) acc[c][j] = bv;
    }

    const int ihb = oh0t * S - PAD;
    const int iwb = ow0t * S - PAD;
    const long inHW = (long)Hin * Win;
    const int KK  = K * K;
    const int wCK = Cin * KK;

    for (int ci0 = 0; ci0 < Cin; ci0 += NCI) {
        __syncthreads();
        for (int e = t; e < NCI * ITT; e += 256) {
            int c  = e / ITT, r = e - c * ITT;
            int rr = r / IT,  cc = r - rr * IT;
            int ih = ihb + rr, iw = iwb + cc;
            TAcc v = (TAcc)0;
            if ((unsigned)ih < (unsigned)Hin && (unsigned)iw < (unsigned)Win)
                v = (TAcc)in[((long)b * Cin + ci0 + c) * inHW + (long)ih * Win + iw];
            if (IN_RELU) v = maxT(v, (TAcc)0);
            tile[e] = v;
        }
        __syncthreads();
        #pragma unroll
        for (int c = 0; c < NCI; c++) {
            const float* wp = w + ((long)co0 * Cin + (ci0 + c)) * KK;
            #pragma unroll
            for (int kh = 0; kh < K; kh++) {
                const TAcc* rp = tile + c * ITT + (loh * S + kh) * IT + lowg * PIX * S;
                TAcc iv[WIN];
                #pragma unroll
                for (int x = 0; x < WIN; x++) iv[x] = rp[x];
                #pragma unroll
                for (int c2 = 0; c2 < CPW; c2++) {
                    #pragma unroll
                    for (int kw = 0; kw < K; kw++) {
                        TAcc wv = (TAcc)wp[c2 * wCK + kh * K + kw];
                        #pragma unroll
                        for (int j = 0; j < PIX; j++)
                            acc[c2][j] = fmaT(iv[j * S + kw], wv, acc[c2][j]);
                    }
                }
            }
        }
    }

    long ostride = (long)Hout * Wout;
    long obase = (((long)b * Cout + co0) * Hout + oh) * Wout + ow0;
    #pragma unroll
    for (int c = 0; c < CPW; c++) {
        #pragma unroll
        for (int j = 0; j < PIX; j++) {
            TAcc v = acc[c][j];
            if (RES_ADD) v += res[obase + c * ostride + j];
            if (OUT_RELU) v = maxT(v, (TAcc)0);
            out[obase + c * ostride + j] = (TOut)v;
        }
    }
}

// ---------------------------------------------------------------------------
// LDS-tiled ConvTranspose2d k=4 s=2 p=1, fp32. Weight (Cin, Cout, 4, 4).
// 256 threads; each thread owns input pos (tiy,tix) of a 16x16 input tile
// (18x18 with halo in LDS) and computes the 2x2 output quad (2*iy..+1,
// 2*ix..+1) for CQ output channels. Per-output fmaf chains replicate
// deconv4x4s2 exactly:
//   even oh: kh=1 (row iy) then kh=3 (row iy-1); odd oh: kh=0 (iy+1), kh=2 (iy)
//   even ow: +i[iw-1]*w[kh][3] then +i[iw]*w[kh][1]
//   odd  ow: +i[iw]*w[kh][2]  then +i[iw+1]*w[kh][0]
// Halo zeros == original's OOB skip (fma(0,w,acc)).
// ---------------------------------------------------------------------------
template<int CQ, bool IN_RELU, bool OUT_RELU, bool OUT_TANH, int NCI>
__global__ __launch_bounds__(256, 3)
void deconv_tiled(const float* __restrict__ in, const float* __restrict__ w,
                  const float* __restrict__ bias, float* __restrict__ out,
                  int B, int Cin, int Hin, int Win, int Cout)
{
    constexpr int IT  = 18;          // 16 + 2 halo
    constexpr int ITT = IT * IT;
    int Hout = Hin << 1, Wout = Win << 1;

    __shared__ float tile[NCI * ITT];

    int ntx = Win >> 4, nty = Hin >> 4, ncb = Cout / CQ;
    int g = blockIdx.x;
    int tx = g % ntx; g /= ntx;
    int ty = g % nty; g /= nty;
    int cb = g % ncb;
    int b  = g / ncb;

    int t   = threadIdx.x;
    int tix = t & 15;
    int tiy = t >> 4;
    int ix0 = tx << 4, iy0 = ty << 4;
    int co0 = cb * CQ;

    float acc[CQ][4];
    #pragma unroll
    for (int c = 0; c < CQ; c++) {
        float bv = bias[co0 + c];
        #pragma unroll
        for (int j = 0; j < 4; j++) acc[c][j] = bv;
    }

    const long inHW = (long)Hin * Win;

    for (int ci0 = 0; ci0 < Cin; ci0 += NCI) {
        __syncthreads();
        for (int e = t; e < NCI * ITT; e += 256) {
            int c  = e / ITT, r = e - c * ITT;
            int rr = r / IT,  cc = r - rr * IT;
            int ih = iy0 - 1 + rr, iw = ix0 - 1 + cc;
            float v = 0.f;
            if ((unsigned)ih < (unsigned)Hin && (unsigned)iw < (unsigned)Win)
                v = in[((long)b * Cin + ci0 + c) * inHW + (long)ih * Win + iw];
            if (IN_RELU) v = fmaxf(v, 0.f);
            tile[e] = v;
        }
        __syncthreads();
        #pragma unroll
        for (int c = 0; c < NCI; c++) {
            const float* tp = tile + c * ITT + tiy * IT + tix;
            float n00 = tp[0],        n01 = tp[1],        n02 = tp[2];
            float n10 = tp[IT],       n11 = tp[IT + 1],   n12 = tp[IT + 2];
            float n20 = tp[2 * IT],   n21 = tp[2 * IT + 1], n22 = tp[2 * IT + 2];
            const float* wb = w + ((long)(ci0 + c) * Cout + co0) * 16;
            #pragma unroll
            for (int cq = 0; cq < CQ; cq++) {
                const float* wk = wb + cq * 16;
                float a0 = acc[cq][0], a1 = acc[cq][1];
                float a2 = acc[cq][2], a3 = acc[cq][3];
                // out(2iy, 2ix): kh=1 row iy; kh=3 row iy-1
                a0 = fmaf(n11, wk[5],  fmaf(n10, wk[7],  a0));
                a0 = fmaf(n01, wk[13], fmaf(n00, wk[15], a0));
                // out(2iy, 2ix+1)
                a1 = fmaf(n12, wk[4],  fmaf(n11, wk[6],  a1));
                a1 = fmaf(n02, wk[12], fmaf(n01, wk[14], a1));
                // out(2iy+1, 2ix): kh=0 row iy+1; kh=2 row iy
                a2 = fmaf(n21, wk[1],  fmaf(n20, wk[3],  a2));
                a2 = fmaf(n11, wk[9],  fmaf(n10, wk[11], a2));
                // out(2iy+1, 2ix+1)
                a3 = fmaf(n22, wk[0],  fmaf(n21, wk[2],  a3));
                a3 = fmaf(n12, wk[8],  fmaf(n11, wk[10], a3));
                acc[cq][0] = a0; acc[cq][1] = a1;
                acc[cq][2] = a2; acc[cq][3] = a3;
            }
        }
    }

    int oh0 = (iy0 + tiy) << 1;
    int ow0 = (ix0 + tix) << 1;
    long ostride = (long)Hout * Wout;
    long obase = (((long)b * Cout + co0) * Hout + oh0) * Wout + ow0;
    #pragma unroll
    for (int c = 0; c < CQ; c++) {
        #pragma unroll
        for (int j = 0; j < 4; j++) {
            float v = acc[c][j];
            if (OUT_RELU) v = fmaxf(v, 0.f);
            if (OUT_TANH) v = tanhf(v);
            out[obase + c * ostride + (j >> 1) * (long)Wout + (j & 1)] = v;
        }
    }
}

// numpy pairwise sum-of-squares over 64 fp32 values.
__device__ __forceinline__ float np_sumsq64(const float* v) {
    float r[8];
    #pragma unroll
    for (int j = 0; j < 8; j++) r[j] = __fmul_rn(v[j], v[j]);
    #pragma unroll
    for (int i = 8; i < 64; i += 8) {
        #pragma unroll
        for (int j = 0; j < 8; j++)
            r[j] = __fadd_rn(r[j], __fmul_rn(v[i + j], v[i + j]));
    }
    float s01 = __fadd_rn(r[0], r[1]), s23 = __fadd_rn(r[2], r[3]);
    float s45 = __fadd_rn(r[4], r[5]), s67 = __fadd_rn(r[6], r[7]);
    return __fadd_rn(__fadd_rn(s01, s23), __fadd_rn(s45, s67));
}

__global__ void codenorm_kernel(const float* __restrict__ cb, float* __restrict__ cn)
{
    int k = blockIdx.x * 64 + threadIdx.x;
    if (k >= 512) return;
    float row[64];
    #pragma unroll
    for (int d = 0; d < 64; d++) row[d] = cb[k * 64 + d];
    cn[k] = np_sumsq64(row);
}

// VQ: np-exact fp32 chain; st = fl(z + fl(q-z)).
// z loads coalesced via LDS transpose (bit-identical values). k-loop 4-way
// unrolled: each k's fmaf chain is unchanged; strict-< scan in k order.
__global__ __launch_bounds__(256)
void vq_kernel(const float* __restrict__ z, const float* __restrict__ cb,
               const float* __restrict__ cn, float* __restrict__ st,
               double* __restrict__ loss_sum, int B)
{
    __shared__ float zt[64][256];
    int t = threadIdx.x;
    long pg = (long)blockIdx.x * 256;
    int b = (int)(pg >> 12);
    int p0 = (int)(pg & 4095);
    const float* zb = z + (long)b * 64 * 4096 + p0;
    #pragma unroll
    for (int d = 0; d < 64; d++) zt[d][t] = zb[(long)d * 4096 + t];
    __syncthreads();

    int p = p0 + t;
    float zr[64];
    #pragma unroll
    for (int d = 0; d < 64; d++) zr[d] = zt[d][t];

    float s1 = np_sumsq64(zr);

    float best = INFINITY;
    int bi = 0;
    for (int k = 0; k < 512; k += 4) {
        const float* c0 = cb + (k + 0) * 64;
        const float* c1 = cb + (k + 1) * 64;
        const float* c2 = cb + (k + 2) * 64;
        const float* c3 = cb + (k + 3) * 64;
        float m0 = 0.f, m1 = 0.f, m2 = 0.f, m3 = 0.f;
        #pragma unroll
        for (int d = 0; d < 64; d++) {
            float zd = zr[d];
            m0 = fmaf(zd, c0[d], m0);
            m1 = fmaf(zd, c1[d], m1);
            m2 = fmaf(zd, c2[d], m2);
            m3 = fmaf(zd, c3[d], m3);
        }
        float d0 = __fadd_rn(__fsub_rn(s1, __fmul_rn(2.f, m0)), cn[k + 0]);
        float d1 = __fadd_rn(__fsub_rn(s1, __fmul_rn(2.f, m1)), cn[k + 1]);
        float d2 = __fadd_rn(__fsub_rn(s1, __fmul_rn(2.f, m2)), cn[k + 2]);
        float d3 = __fadd_rn(__fsub_rn(s1, __fmul_rn(2.f, m3)), cn[k + 3]);
        if (d0 < best) { best = d0; bi = k + 0; }
        if (d1 < best) { best = d1; bi = k + 1; }
        if (d2 < best) { best = d2; bi = k + 2; }
        if (d3 < best) { best = d3; bi = k + 3; }
    }

    const float* cbest = cb + bi * 64;
    float* sp = st + (long)b * 64 * 4096 + p;
    double ls = 0.0;
    #pragma unroll
    for (int d = 0; d < 64; d++) {
        float qv = cbest[d];
        float zv = zr[d];
        float diff = __fsub_rn(qv, zv);
        double dd = (double)qv - (double)zv;
        ls += dd * dd;
        sp[(long)d * 4096] = __fadd_rn(zv, diff);
    }
    #pragma unroll
    for (int off = 32; off > 0; off >>= 1) ls += __shfl_down(ls, off, 64);
    if ((t & 63) == 0) atomicAdd(loss_sum, ls);
}

__global__ void loss_final_kernel(const double* __restrict__ s, float* __restrict__ out)
{
    out[0] = (float)(1.25 * s[0] / 8388608.0);   // fp32 loss store
}

extern "C" void kernel_launch(void* const* d_in, const int* in_sizes, int n_in,
                              void* d_out, int out_size, void* d_ws, size_t ws_size,
                              hipStream_t stream)
{
    const float* x        = (const float*)d_in[0];
    const float* enc_w1   = (const float*)d_in[1];
    const float* enc_b1   = (const float*)d_in[2];
    const float* enc_w2   = (const float*)d_in[3];
    const float* enc_b2   = (const float*)d_in[4];
    const float* enc_w3   = (const float*)d_in[5];
    const float* enc_b3   = (const float*)d_in[6];
    const float* enc_rw1  = (const float*)d_in[7];
    const float* enc_rb1  = (const float*)d_in[8];
    const float* enc_rw2  = (const float*)d_in[9];
    const float* enc_rb2  = (const float*)d_in[10];
    const float* pvq_w    = (const float*)d_in[11];
    const float* pvq_b    = (const float*)d_in[12];
    const float* codebook = (const float*)d_in[13];
    const float* dec_w1   = (const float*)d_in[14];
    const float* dec_b1   = (const float*)d_in[15];
    const float* dec_rw1  = (const float*)d_in[16];
    const float* dec_rb1  = (const float*)d_in[17];
    const float* dec_rw2  = (const float*)d_in[18];
    const float* dec_rb2  = (const float*)d_in[19];
    const float* dt1_w    = (const float*)d_in[20];
    const float* dt1_b    = (const float*)d_in[21];
    const float* dt2_w    = (const float*)d_in[22];
    const float* dt2_b    = (const float*)d_in[23];

    float* out = (float*)d_out;            // fp32 output buffer (ref dtype)
    char* wsb = (char*)d_ws;

    float*  CN = (float*)wsb;              // 512 floats
    double* LS = (double*)(wsb + 4096);    // 1 double
    const size_t SMALLB = 4352;

    const long eA = 1048576, eB = 524288, eC = 524288, eT = 131072;
    const long eZ = 262144, eQ = 262144;
    const size_t perSampleB = (size_t)(eA + eB + eC + eT) * 8 + (size_t)(eZ + eQ) * 4;

    int Bc = 32;
    while (Bc > 1 && SMALLB + perSampleB * Bc + 1024 > ws_size) Bc >>= 1;
    const int nChunks = 32 / Bc;

    double* A64 = (double*)(wsb + SMALLB);
    double* B64 = A64 + eA * Bc;
    double* C64 = B64 + eB * Bc;
    double* T64 = C64 + eC * Bc;
    float*  Z32 = (float*)(T64 + eT * Bc);
    float*  Qf  = Z32 + eZ * Bc;
    float* Df = (float*)B64;   // decoder fp32 aliases (encoder buffers dead)
    float* Tf = (float*)T64;
    float* Ef = (float*)A64;

    hipMemsetAsync(LS, 0, sizeof(double), stream);
    codenorm_kernel<<<8, 64, 0, stream>>>(codebook, CN);

    for (int c = 0; c < nChunks; c++) {
        const float* xc = x + (long)c * Bc * 3 * 65536;
        float* outc = out + (long)c * Bc * 3 * 65536;

        // ---- encoder (fp64 accumulate -> fp32 z) ----
        // enc1: 4x4 s2 3->64, 256->128, OUT_RELU. NCI=3 (single stage round).
        conv_tiled<float,double,double,4,2,1,false,true,false,3,32>
            <<<Bc*8*8*2, 256, 0, stream>>>(
            xc, enc_w1, enc_b1, nullptr, A64, Bc, 3, 256, 256, 64, 128, 128);
        // enc2: 4x4 s2 64->128, 128->64, OUT_RELU.
        conv_tiled<double,double,double,4,2,1,false,true,false,2,32>
            <<<Bc*4*4*4, 256, 0, stream>>>(
            A64, enc_w2, enc_b2, nullptr, B64, Bc, 64, 128, 128, 128, 64, 64);
        // enc3: 3x3 s1 128->128.
        conv_tiled<double,double,double,3,1,1,false,false,false,4,32>
            <<<Bc*4*4*4, 256, 0, stream>>>(
            B64, enc_w3, enc_b3, nullptr, C64, Bc, 128, 64, 64, 128, 64, 64);
        for (int i = 0; i < 2; i++) {
            // res1: 3x3 128->32, IN_RELU. COB=16 for grid occupancy.
            conv_tiled<double,double,double,3,1,1,true,false,false,4,16>
                <<<Bc*4*4*2, 256, 0, stream>>>(
                C64, enc_rw1 + (long)i*32*128*9, enc_rb1 + i*32, nullptr, T64,
                Bc, 128, 64, 64, 32, 64, 64);
            // res2: 1x1 32->128, IN_RELU, +residual C64, in-place C64.
            conv_tiled<double,double,double,1,1,0,true,false,true,16,32>
                <<<Bc*4*4*4, 256, 0, stream>>>(
                T64, enc_rw2 + (long)i*128*32, enc_rb2 + i*128, C64, C64,
                Bc, 32, 64, 64, 128, 64, 64);
        }
        // pvq: 1x1 128->64, IN_RELU, fp32 store.
        conv_tiled<double,double,float,1,1,0,true,false,false,16,32>
            <<<Bc*4*4*2, 256, 0, stream>>>(
            C64, pvq_w, pvq_b, nullptr, Z32, Bc, 128, 64, 64, 64, 64, 64);

        // ---- VQ (np-exact fp32) ----
        vq_kernel<<<Bc * 16, 256, 0, stream>>>(Z32, codebook, CN, Qf, LS, Bc);

        // ---- decoder (fp32), fp32 output stores ----
        conv_tiled<float,float,float,3,1,1,false,false,false,8,32>
            <<<Bc*4*4*4, 256, 0, stream>>>(
            Qf, dec_w1, dec_b1, nullptr, Df, Bc, 64, 64, 64, 128, 64, 64);
        for (int i = 0; i < 2; i++) {
            conv_tiled<float,float,float,3,1,1,true,false,false,8,16>
                <<<Bc*4*4*2, 256, 0, stream>>>(
                Df, dec_rw1 + (long)i*32*128*9, dec_rb1 + i*32, nullptr, Tf,
                Bc, 128, 64, 64, 32, 64, 64);
            conv_tiled<float,float,float,1,1,0,true,false,true,16,32>
                <<<Bc*4*4*4, 256, 0, stream>>>(
                Tf, dec_rw2 + (long)i*128*32, dec_rb2 + i*128, Df, Df,
                Bc, 32, 64, 64, 128, 64, 64);
        }
        // dt1: deconv 128->64, 64->128, IN_RELU + OUT_RELU.
        deconv_tiled<8,true,true,false,8><<<Bc*4*4*8, 256, 0, stream>>>(
            Df, dt1_w, dt1_b, Ef, Bc, 128, 64, 64, 64);
        // dt2: deconv 64->3, 128->256, tanh, writes final output.
        deconv_tiled<3,false,false,true,8><<<Bc*8*8*1, 256, 0, stream>>>(
            Ef, dt2_w, dt2_b, outc, Bc, 64, 128, 128, 3);
    }

    loss_final_kernel<<<1, 1, 0, stream>>>(LS, out + 6291456);
}